// Round 2
// baseline (425.533 us; speedup 1.0000x reference)
//
#include <hip/hip_runtime.h>

#define BATCH 4096
#define NGC   8192
#define NPC   2048

typedef _Float16 f16;
typedef __attribute__((ext_vector_type(8))) _Float16 f16x8;
typedef __attribute__((ext_vector_type(4))) _Float16 f16x4;
typedef __attribute__((ext_vector_type(4))) float   floatx4;

__device__ __forceinline__ float softplus_f(float x) {
    // jax.nn.softplus = log1p(exp(-|x|)) + max(x, 0)
    return fmaxf(x, 0.0f) + log1pf(expf(-fabsf(x)));
}

// ---- prep: merged conversion kernel ----------------------------------------
// Grid-stride, 2048 blocks x 256 thr (Guideline 11). Each chunk = 4 f32 ->
// 4 f16 (16B coalesced load, 8B coalesced store).
//   chunks [0, GH_CH):          gh = (f16)g
//   chunks [GH_CH, GH_CH+WH_CH): wh = (f16)(softplus(W)*mask)
#define GH_CH ((BATCH * NGC) / 4)   // 8,388,608
#define WH_CH ((NPC * NGC) / 4)     // 4,194,304

__global__ __launch_bounds__(256)
void prep(const float* __restrict__ g, const float* __restrict__ W,
          const float* __restrict__ mask,
          f16* __restrict__ gh, f16* __restrict__ wh) {
    const int stride = gridDim.x * blockDim.x;
    for (int c = blockIdx.x * blockDim.x + threadIdx.x;
         c < GH_CH + WH_CH; c += stride) {
        if (c < GH_CH) {
            float4 v = *(const float4*)(g + (size_t)c * 4);
            f16x4 h;
            h[0] = (f16)v.x; h[1] = (f16)v.y; h[2] = (f16)v.z; h[3] = (f16)v.w;
            *(f16x4*)(gh + (size_t)c * 4) = h;
        } else {
            size_t d = (size_t)(c - GH_CH) * 4;
            float4 w = *(const float4*)(W + d);
            float4 m = *(const float4*)(mask + d);
            f16x4 h;
            h[0] = (f16)(softplus_f(w.x) * m.x);
            h[1] = (f16)(softplus_f(w.y) * m.y);
            h[2] = (f16)(softplus_f(w.z) * m.z);
            h[3] = (f16)(softplus_f(w.w) * m.w);
            *(f16x4*)(wh + d) = h;
        }
    }
}

// ---- main GEMM -------------------------------------------------------------
// out[b][p] = relu(sum_k A[b][k]*B[p][k] + bias[p])
//
// v3 = v2 (counted-vmcnt 3-buffer pipeline, 256x128 tile, 8 waves) + T1
// XCD-chunked block swizzle: HW assigns XCD = dispatch_lin % 8; remap so each
// XCD's 32 resident blocks cover exactly 2 consecutive by-rows -> the 4 MB
// f16 A-panels become L2-resident per XCD instead of being re-fetched from
// L3/HBM by all 8 XCDs.
//
//   Pipeline recap (verified r1: MfmaUtil 43->46, 0 bank conflicts, passed):
//   three rotating 48KB K-tile buffers; while computing tile t, tile t+1 is
//   fully in flight and tile t+2's loads issue into the buffer freed by t-1.
//   Top of tile t: s_waitcnt vmcnt(6) (t+1's 6 loads stay flying) + one
//   s_barrier. No vmcnt(0) drain in the main loop.
__device__ __forceinline__ void gload_lds16(const f16* g, f16* l) {
    __builtin_amdgcn_global_load_lds((const __attribute__((address_space(1))) void*)g,
                                     (__attribute__((address_space(3))) void*)l,
                                     16, 0, 0);
}

#define ABUF  (256 * 64)          // f16 elems per A tile (32 KB)
#define BBUF  (128 * 64)          // f16 elems per B tile (16 KB)
#define BUFSZ (ABUF + BBUF)       // 24576 f16 = 48 KB
#define NT    (NGC / 64)          // 128 K-tiles

// A tile: 2048 chunks of 16B -> 4 loads/thread; B tile: 1024 -> 2 loads/thread.
// XOR-swizzled global fetch, linear LDS dst: chunk d holds k-group (d&7)^(r&7).
#define STAGE_A(kt, sbuf, i) do {                                              \
    int d_ = tid + 512 * (i);                                                  \
    int r_ = d_ >> 3;                                                          \
    int g_ = (d_ & 7) ^ (r_ & 7);                                              \
    gload_lds16(A + (size_t)(bm0 + r_) * NGC + (kt) * 64 + g_ * 8,             \
                (sbuf) + d_ * 8);                                              \
} while (0)

#define STAGE_B(kt, sbuf, i) do {                                              \
    int d_ = tid + 512 * (i);                                                  \
    int r_ = d_ >> 3;                                                          \
    int g_ = (d_ & 7) ^ (r_ & 7);                                              \
    gload_lds16(B + (size_t)(bn0 + r_) * NGC + (kt) * 64 + g_ * 8,             \
                (sbuf) + ABUF + d_ * 8);                                       \
} while (0)

__global__ __launch_bounds__(512, 2)
void gemm_f16(const f16* __restrict__ A, const f16* __restrict__ B,
              const float* __restrict__ bias, float* __restrict__ out) {
    __shared__ __align__(16) f16 lds[3 * BUFSZ];   // 144 KB

    const int tid  = threadIdx.x;
    const int lane = tid & 63;
    const int wid  = tid >> 6;

    // T1: XCD-chunked swizzle (bijective: 256 blocks, 256 % 8 == 0).
    // lin%8 == XCD; logical ids [x*32, x*32+32) = by-rows {2x, 2x+1}, all bx.
    const int lin     = blockIdx.y * gridDim.x + blockIdx.x;
    const int logical = (lin & 7) * 32 + (lin >> 3);
    const int bm0  = (logical >> 4) * 256;   // batch (by')
    const int bn0  = (logical & 15) * 128;   // pc    (bx')

    const int wm   = (wid >> 1) * 64;    // 4 M-wave groups
    const int wn   = (wid & 1) * 64;     // 2 N-wave groups
    const int l15  = lane & 15;
    const int lq   = lane >> 4;

    floatx4 acc[4][4] = {};

    // prologue: tiles 0 and 1 fully issued (12 loads/thread in flight)
#pragma unroll
    for (int i = 0; i < 4; ++i) STAGE_A(0, lds, i);
#pragma unroll
    for (int i = 0; i < 2; ++i) STAGE_B(0, lds, i);
#pragma unroll
    for (int i = 0; i < 4; ++i) STAGE_A(1, lds + BUFSZ, i);
#pragma unroll
    for (int i = 0; i < 2; ++i) STAGE_B(1, lds + BUFSZ, i);

    int cur = 0;
    for (int t = 0; t < NT; ++t) {
        // counted wait: tile t retired, tile t+1's 6 loads stay in flight.
        if (t + 1 < NT) asm volatile("s_waitcnt vmcnt(6)" ::: "memory");
        else            asm volatile("s_waitcnt vmcnt(0)" ::: "memory");
        __builtin_amdgcn_s_barrier();

        f16* sA = lds + cur * BUFSZ;
        f16* sB = sA + ABUF;
        int st = cur + 2; if (st >= 3) st -= 3;
        f16* stbuf = lds + st * BUFSZ;
        const bool do_stage = (t < NT - 2);

#pragma unroll
        for (int ks = 0; ks < 2; ++ks) {
            const int g = ks * 4 + lq;   // k-group for this lane's fragment
            f16x8 a[4], b[4];
#pragma unroll
            for (int mt = 0; mt < 4; ++mt) {
                int ra = wm + mt * 16 + l15;
                int ca = (ra << 3) | (g ^ (ra & 7));
                a[mt] = *(const f16x8*)(sA + ca * 8);
            }
#pragma unroll
            for (int nt = 0; nt < 4; ++nt) {
                int rb = wn + nt * 16 + l15;
                int cb = (rb << 3) | (g ^ (rb & 7));
                b[nt] = *(const f16x8*)(sB + cb * 8);
            }
            // issue half of tile t+2's staging (3 loads) under this phase's MFMAs
            if (do_stage) {
                STAGE_A(t + 2, stbuf, ks * 2 + 0);
                STAGE_A(t + 2, stbuf, ks * 2 + 1);
                STAGE_B(t + 2, stbuf, ks);
            }
            __builtin_amdgcn_s_setprio(1);
#pragma unroll
            for (int mt = 0; mt < 4; ++mt)
#pragma unroll
                for (int nt = 0; nt < 4; ++nt)
                    acc[mt][nt] = __builtin_amdgcn_mfma_f32_16x16x32_f16(
                        a[mt], b[nt], acc[mt][nt], 0, 0, 0);
            __builtin_amdgcn_s_setprio(0);
        }
        cur += 1; if (cur == 3) cur = 0;
    }

    // epilogue: D layout col=lane&15 (pc), row=(lane>>4)*4+reg (batch)
#pragma unroll
    for (int nt = 0; nt < 4; ++nt) {
        int col  = bn0 + wn + nt * 16 + l15;
        float bv = bias[col];
#pragma unroll
        for (int mt = 0; mt < 4; ++mt) {
#pragma unroll
            for (int r = 0; r < 4; ++r) {
                int row = bm0 + wm + mt * 16 + lq * 4 + r;
                float x = acc[mt][nt][r] + bv;
                out[(size_t)row * NPC + col] = fmaxf(x, 0.0f);
            }
        }
    }
}

// ---- exact fp32 fallback (only if ws too small) ----------------------------
__global__ void naive_kernel(const float* __restrict__ g, const float* __restrict__ W,
                             const float* __restrict__ bias, const float* __restrict__ mask,
                             float* __restrict__ out) {
    int idx = blockIdx.x * 256 + threadIdx.x;   // over BATCH*NPC
    int b = idx / NPC, p = idx % NPC;
    const float* gr = g + (size_t)b * NGC;
    const float* wr = W + (size_t)p * NGC;
    const float* mr = mask + (size_t)p * NGC;
    float acc = bias[p];
    for (int k = 0; k < NGC; ++k) {
        float m = mr[k];
        if (m != 0.0f) acc += gr[k] * softplus_f(wr[k]);
    }
    out[idx] = fmaxf(acc, 0.0f);
}

extern "C" void kernel_launch(void* const* d_in, const int* in_sizes, int n_in,
                              void* d_out, int out_size, void* d_ws, size_t ws_size,
                              hipStream_t stream) {
    const float* g_in  = (const float*)d_in[0];
    const float* W_raw = (const float*)d_in[1];
    const float* b_pc  = (const float*)d_in[2];
    const float* mask  = (const float*)d_in[3];
    float* out = (float*)d_out;

    const size_t gh_elems = (size_t)BATCH * NGC;
    const size_t wh_elems = (size_t)NPC * NGC;
    const size_t need = (gh_elems + wh_elems) * sizeof(f16);   // 96 MB

    if (ws_size >= need) {
        f16* gh = (f16*)d_ws;
        f16* wh = gh + gh_elems;
        prep<<<2048, 256, 0, stream>>>(g_in, W_raw, mask, gh, wh);
        dim3 grid(NPC / 128, BATCH / 256);
        gemm_f16<<<grid, 512, 0, stream>>>(gh, wh, b_pc, out);
    } else {
        naive_kernel<<<BATCH * NPC / 256, 256, 0, stream>>>(g_in, W_raw, b_pc, mask, out);
    }
}

// Round 5
// 407.082 us; speedup vs baseline: 1.0453x; 1.0453x over previous
//
#include <hip/hip_runtime.h>

#define BATCH 4096
#define NGC   8192
#define NPC   2048

typedef _Float16 f16;
typedef __attribute__((ext_vector_type(8))) _Float16 f16x8;
typedef __attribute__((ext_vector_type(4))) _Float16 f16x4;
typedef __attribute__((ext_vector_type(4))) float   floatx4;

// Fast softplus: max(x,0) + ln2*log2(1 + 2^(-|x|*log2e)).
// exp2f/log2f lower to hardware v_exp_f32/v_log_f32 on gfx950 (HW computes
// 2^x and log2 x natively). ~1e-7 rel error, invisible vs the f16
// quantization of the stored weight (which dominates the accepted absmax).
__device__ __forceinline__ float softplus_fast(float x) {
    const float LOG2E = 1.4426950408889634f;
    const float LN2   = 0.6931471805599453f;
    float e = exp2f(__builtin_fabsf(x) * -LOG2E);
    float l = log2f(1.0f + e);
    return fmaxf(x, 0.0f) + l * LN2;
}

// ---- prep: g f32 -> f16, 8 elems/thread (32B load, 16B store per lane) -----
__global__ __launch_bounds__(256)
void cvt_g8(const float* __restrict__ g, f16* __restrict__ gh) {
    size_t i = ((size_t)blockIdx.x * 256 + threadIdx.x) * 8;
    float4 v0 = *(const float4*)(g + i);
    float4 v1 = *(const float4*)(g + i + 4);
    f16x8 h;
    h[0] = (f16)v0.x; h[1] = (f16)v0.y; h[2] = (f16)v0.z; h[3] = (f16)v0.w;
    h[4] = (f16)v1.x; h[5] = (f16)v1.y; h[6] = (f16)v1.z; h[7] = (f16)v1.w;
    *(f16x8*)(gh + i) = h;
}

// ---- prep: wh = f16(softplus_fast(W) * mask), 8 elems/thread ---------------
__global__ __launch_bounds__(256)
void cvt_w8(const float* __restrict__ W, const float* __restrict__ mask,
            f16* __restrict__ wh) {
    size_t i = ((size_t)blockIdx.x * 256 + threadIdx.x) * 8;
    float4 w0 = *(const float4*)(W + i);
    float4 w1 = *(const float4*)(W + i + 4);
    float4 m0 = *(const float4*)(mask + i);
    float4 m1 = *(const float4*)(mask + i + 4);
    f16x8 h;
    h[0] = (f16)(softplus_fast(w0.x) * m0.x);
    h[1] = (f16)(softplus_fast(w0.y) * m0.y);
    h[2] = (f16)(softplus_fast(w0.z) * m0.z);
    h[3] = (f16)(softplus_fast(w0.w) * m0.w);
    h[4] = (f16)(softplus_fast(w1.x) * m1.x);
    h[5] = (f16)(softplus_fast(w1.y) * m1.y);
    h[6] = (f16)(softplus_fast(w1.z) * m1.z);
    h[7] = (f16)(softplus_fast(w1.w) * m1.w);
    *(f16x8*)(wh + i) = h;
}

// ---- main GEMM (unchanged: verified counted-vmcnt pipeline + T1 swizzle) ---
// out[b][p] = relu(sum_k A[b][k]*B[p][k] + bias[p])
// 256x128 tile, BK=64, 8 waves (4Mx2N of 64x64), 16x16x32 f16 MFMA.
// Three rotating 48KB K-tile buffers; computing tile t while t+1 is fully in
// flight and t+2 stages into the buffer freed by t-1. Top of tile t:
// s_waitcnt vmcnt(6) + one s_barrier; no vmcnt(0) drain in the main loop.
// T1 XCD-chunked swizzle: each XCD's 32 resident blocks cover 2 by-rows
// (gemm FETCH 295 -> 171 MB, verified r2).
__device__ __forceinline__ void gload_lds16(const f16* g, f16* l) {
    __builtin_amdgcn_global_load_lds((const __attribute__((address_space(1))) void*)g,
                                     (__attribute__((address_space(3))) void*)l,
                                     16, 0, 0);
}

#define ABUF  (256 * 64)          // f16 elems per A tile (32 KB)
#define BBUF  (128 * 64)          // f16 elems per B tile (16 KB)
#define BUFSZ (ABUF + BBUF)       // 24576 f16 = 48 KB
#define NT    (NGC / 64)          // 128 K-tiles

// XOR-swizzled global fetch, linear LDS dst: chunk d holds k-group (d&7)^(r&7).
#define STAGE_A(kt, sbuf, i) do {                                              \
    int d_ = tid + 512 * (i);                                                  \
    int r_ = d_ >> 3;                                                          \
    int g_ = (d_ & 7) ^ (r_ & 7);                                              \
    gload_lds16(A + (size_t)(bm0 + r_) * NGC + (kt) * 64 + g_ * 8,             \
                (sbuf) + d_ * 8);                                              \
} while (0)

#define STAGE_B(kt, sbuf, i) do {                                              \
    int d_ = tid + 512 * (i);                                                  \
    int r_ = d_ >> 3;                                                          \
    int g_ = (d_ & 7) ^ (r_ & 7);                                              \
    gload_lds16(B + (size_t)(bn0 + r_) * NGC + (kt) * 64 + g_ * 8,             \
                (sbuf) + ABUF + d_ * 8);                                       \
} while (0)

__global__ __launch_bounds__(512, 2)
void gemm_f16(const f16* __restrict__ A, const f16* __restrict__ B,
              const float* __restrict__ bias, float* __restrict__ out) {
    __shared__ __align__(16) f16 lds[3 * BUFSZ];   // 144 KB

    const int tid  = threadIdx.x;
    const int lane = tid & 63;
    const int wid  = tid >> 6;

    // T1: XCD-chunked swizzle (bijective: 256 blocks, 256 % 8 == 0).
    const int lin     = blockIdx.y * gridDim.x + blockIdx.x;
    const int logical = (lin & 7) * 32 + (lin >> 3);
    const int bm0  = (logical >> 4) * 256;   // batch (by')
    const int bn0  = (logical & 15) * 128;   // pc    (bx')

    const int wm   = (wid >> 1) * 64;    // 4 M-wave groups
    const int wn   = (wid & 1) * 64;     // 2 N-wave groups
    const int l15  = lane & 15;
    const int lq   = lane >> 4;

    floatx4 acc[4][4] = {};

    // prologue: tiles 0 and 1 fully issued (12 loads/thread in flight)
#pragma unroll
    for (int i = 0; i < 4; ++i) STAGE_A(0, lds, i);
#pragma unroll
    for (int i = 0; i < 2; ++i) STAGE_B(0, lds, i);
#pragma unroll
    for (int i = 0; i < 4; ++i) STAGE_A(1, lds + BUFSZ, i);
#pragma unroll
    for (int i = 0; i < 2; ++i) STAGE_B(1, lds + BUFSZ, i);

    int cur = 0;
    for (int t = 0; t < NT; ++t) {
        // counted wait: tile t retired, tile t+1's 6 loads stay in flight.
        if (t + 1 < NT) asm volatile("s_waitcnt vmcnt(6)" ::: "memory");
        else            asm volatile("s_waitcnt vmcnt(0)" ::: "memory");
        __builtin_amdgcn_s_barrier();

        f16* sA = lds + cur * BUFSZ;
        f16* sB = sA + ABUF;
        int st = cur + 2; if (st >= 3) st -= 3;
        f16* stbuf = lds + st * BUFSZ;
        const bool do_stage = (t < NT - 2);

#pragma unroll
        for (int ks = 0; ks < 2; ++ks) {
            const int g = ks * 4 + lq;   // k-group for this lane's fragment
            f16x8 a[4], b[4];
#pragma unroll
            for (int mt = 0; mt < 4; ++mt) {
                int ra = wm + mt * 16 + l15;
                int ca = (ra << 3) | (g ^ (ra & 7));
                a[mt] = *(const f16x8*)(sA + ca * 8);
            }
#pragma unroll
            for (int nt = 0; nt < 4; ++nt) {
                int rb = wn + nt * 16 + l15;
                int cb = (rb << 3) | (g ^ (rb & 7));
                b[nt] = *(const f16x8*)(sB + cb * 8);
            }
            // issue half of tile t+2's staging (3 loads) under this phase's MFMAs
            if (do_stage) {
                STAGE_A(t + 2, stbuf, ks * 2 + 0);
                STAGE_A(t + 2, stbuf, ks * 2 + 1);
                STAGE_B(t + 2, stbuf, ks);
            }
            __builtin_amdgcn_s_setprio(1);
#pragma unroll
            for (int mt = 0; mt < 4; ++mt)
#pragma unroll
                for (int nt = 0; nt < 4; ++nt)
                    acc[mt][nt] = __builtin_amdgcn_mfma_f32_16x16x32_f16(
                        a[mt], b[nt], acc[mt][nt], 0, 0, 0);
            __builtin_amdgcn_s_setprio(0);
        }
        cur += 1; if (cur == 3) cur = 0;
    }

    // epilogue: D layout col=lane&15 (pc), row=(lane>>4)*4+reg (batch)
#pragma unroll
    for (int nt = 0; nt < 4; ++nt) {
        int col  = bn0 + wn + nt * 16 + l15;
        float bv = bias[col];
#pragma unroll
        for (int mt = 0; mt < 4; ++mt) {
#pragma unroll
            for (int r = 0; r < 4; ++r) {
                int row = bm0 + wm + mt * 16 + lq * 4 + r;
                float x = acc[mt][nt][r] + bv;
                out[(size_t)row * NPC + col] = fmaxf(x, 0.0f);
            }
        }
    }
}

// ---- exact fp32 fallback (only if ws too small) ----------------------------
__global__ void naive_kernel(const float* __restrict__ g, const float* __restrict__ W,
                             const float* __restrict__ bias, const float* __restrict__ mask,
                             float* __restrict__ out) {
    int idx = blockIdx.x * 256 + threadIdx.x;   // over BATCH*NPC
    int b = idx / NPC, p = idx % NPC;
    const float* gr = g + (size_t)b * NGC;
    const float* wr = W + (size_t)p * NGC;
    const float* mr = mask + (size_t)p * NGC;
    float acc = bias[p];
    for (int k = 0; k < NGC; ++k) {
        float m = mr[k];
        if (m != 0.0f) acc += gr[k] * (fmaxf(wr[k], 0.0f) + log1pf(expf(-fabsf(wr[k]))));
    }
    out[idx] = fmaxf(acc, 0.0f);
}

extern "C" void kernel_launch(void* const* d_in, const int* in_sizes, int n_in,
                              void* d_out, int out_size, void* d_ws, size_t ws_size,
                              hipStream_t stream) {
    const float* g_in  = (const float*)d_in[0];
    const float* W_raw = (const float*)d_in[1];
    const float* b_pc  = (const float*)d_in[2];
    const float* mask  = (const float*)d_in[3];
    float* out = (float*)d_out;

    const size_t gh_elems = (size_t)BATCH * NGC;
    const size_t wh_elems = (size_t)NPC * NGC;
    const size_t need = (gh_elems + wh_elems) * sizeof(f16);   // 96 MB

    if (ws_size >= need) {
        f16* gh = (f16*)d_ws;
        f16* wh = gh + gh_elems;
        cvt_g8<<<(int)(gh_elems / 2048), 256, 0, stream>>>(g_in, gh);
        cvt_w8<<<(int)(wh_elems / 2048), 256, 0, stream>>>(W_raw, mask, wh);
        dim3 grid(NPC / 128, BATCH / 256);
        gemm_f16<<<grid, 512, 0, stream>>>(gh, wh, b_pc, out);
    } else {
        naive_kernel<<<BATCH * NPC / 256, 256, 0, stream>>>(g_in, W_raw, b_pc, mask, out);
    }
}